// Round 1
// baseline (629.158 us; speedup 1.0000x reference)
//
#include <hip/hip_runtime.h>

#define WALK_LEN 7
#define DIM 128
#define EPSF 1e-15f

// One half-wave (32 lanes) per walk. Each lane holds float4 = 4 floats of the
// 128-float row (32*4 = 128). h_start kept in registers across the 6 scores.
__global__ __launch_bounds__(256) void mp2v_loss_kernel(
    const float* __restrict__ emb,
    const int* __restrict__ pos_rw,
    const int* __restrict__ neg_rw,
    int n_pos, int n_neg,
    float* __restrict__ acc)
{
    const int tid = threadIdx.x;
    const int sub = tid & 31;                      // lane within half-wave
    const int hw_in_block = tid >> 5;              // 0..7 for 256 threads
    const int ghw = blockIdx.x * (blockDim.x >> 5) + hw_in_block;
    const int n_hw = gridDim.x * (blockDim.x >> 5);
    const int total = n_pos + n_neg;

    float acc_pos = 0.0f;
    float acc_neg = 0.0f;

    for (int w = ghw; w < total; w += n_hw) {
        const bool is_pos = (w < n_pos);
        const int* rw = is_pos ? (pos_rw + (size_t)w * WALK_LEN)
                               : (neg_rw + (size_t)(w - n_pos) * WALK_LEN);
        const int i0 = rw[0];
        const float4 hs = ((const float4*)(emb + (size_t)i0 * DIM))[sub];

        #pragma unroll
        for (int c = 1; c < WALK_LEN; ++c) {
            const int ic = rw[c];
            const float4 hr = ((const float4*)(emb + (size_t)ic * DIM))[sub];
            float p = hs.x * hr.x + hs.y * hr.y + hs.z * hr.z + hs.w * hr.w;
            // reduce across the 32-lane half-wave (masks 1..16 stay in-half)
            p += __shfl_xor(p, 1);
            p += __shfl_xor(p, 2);
            p += __shfl_xor(p, 4);
            p += __shfl_xor(p, 8);
            p += __shfl_xor(p, 16);
            // transform: match reference formula exactly in f32
            const float s = 1.0f / (1.0f + __expf(-p));
            const float term = is_pos ? __logf(s + EPSF)
                                      : __logf(1.0f - s + EPSF);
            if (sub == 0) {
                if (is_pos) acc_pos += term;
                else        acc_neg += term;
            }
        }
    }

    // full 64-lane wave reduction (non-sub0 lanes hold 0)
    #pragma unroll
    for (int m = 1; m < 64; m <<= 1) {
        acc_pos += __shfl_xor(acc_pos, m);
        acc_neg += __shfl_xor(acc_neg, m);
    }

    __shared__ float s_pos[4];
    __shared__ float s_neg[4];
    const int wave = tid >> 6;
    if ((tid & 63) == 0) {
        s_pos[wave] = acc_pos;
        s_neg[wave] = acc_neg;
    }
    __syncthreads();
    if (tid == 0) {
        const float bp = s_pos[0] + s_pos[1] + s_pos[2] + s_pos[3];
        const float bn = s_neg[0] + s_neg[1] + s_neg[2] + s_neg[3];
        atomicAdd(&acc[0], bp);
        atomicAdd(&acc[1], bn);
    }
}

__global__ void mp2v_finalize_kernel(const float* __restrict__ acc,
                                     float* __restrict__ out,
                                     float inv_pos, float inv_neg)
{
    // pos_loss = -mean(log(sig+eps)); neg_loss = -mean(log(1-sig+eps))
    out[0] = -(acc[0] * inv_pos) - (acc[1] * inv_neg);
}

extern "C" void kernel_launch(void* const* d_in, const int* in_sizes, int n_in,
                              void* d_out, int out_size, void* d_ws, size_t ws_size,
                              hipStream_t stream) {
    const float* emb    = (const float*)d_in[0];
    const int*   pos_rw = (const int*)d_in[1];
    const int*   neg_rw = (const int*)d_in[2];
    const int n_pos = in_sizes[1] / WALK_LEN;   // 81920
    const int n_neg = in_sizes[2] / WALK_LEN;   // 409600

    float* acc = (float*)d_ws;
    hipMemsetAsync(acc, 0, 2 * sizeof(float), stream);

    const int block = 256;
    const int grid = 2560;   // ~10 blocks/CU, grid-stride over 491520 walks
    mp2v_loss_kernel<<<grid, block, 0, stream>>>(emb, pos_rw, neg_rw,
                                                 n_pos, n_neg, acc);

    const float inv_pos = 1.0f / (float)(n_pos * (WALK_LEN - 1));
    const float inv_neg = 1.0f / (float)(n_neg * (WALK_LEN - 1));
    mp2v_finalize_kernel<<<1, 1, 0, stream>>>(acc, (float*)d_out,
                                              inv_pos, inv_neg);
}

// Round 2
// 517.176 us; speedup vs baseline: 1.2165x; 1.2165x over previous
//
#include <hip/hip_runtime.h>

#define WALK_LEN 7
#define DIM 128
#define EPSF 1e-15f
#define N_ELEM 64000128      // 500001 * 128
#define TAB_OFF 256          // bf16 table offset within d_ws (bytes)

// ---------- f32 -> bf16 (RNE) ----------
__device__ __forceinline__ unsigned short f2bf(float f) {
    unsigned int u = __float_as_uint(f);
    unsigned int r = u + 0x7fffu + ((u >> 16) & 1u);
    return (unsigned short)(r >> 16);
}
__device__ __forceinline__ float bf_lo(unsigned int u) {   // low 16 bits -> f32
    return __uint_as_float(u << 16);
}
__device__ __forceinline__ float bf_hi(unsigned int u) {   // high 16 bits -> f32
    return __uint_as_float(u & 0xffff0000u);
}

// Streaming convert: read 2x float4, write uint4 (8 bf16) per iteration.
__global__ __launch_bounds__(256) void mp2v_convert_kernel(
    const float* __restrict__ emb, uint4* __restrict__ tab, int n8)
{
    int i = blockIdx.x * blockDim.x + threadIdx.x;
    const int stride = gridDim.x * blockDim.x;
    for (; i < n8; i += stride) {
        const float4 a = ((const float4*)emb)[2 * i];
        const float4 b = ((const float4*)emb)[2 * i + 1];
        uint4 o;
        o.x = (unsigned)f2bf(a.x) | ((unsigned)f2bf(a.y) << 16);
        o.y = (unsigned)f2bf(a.z) | ((unsigned)f2bf(a.w) << 16);
        o.z = (unsigned)f2bf(b.x) | ((unsigned)f2bf(b.y) << 16);
        o.w = (unsigned)f2bf(b.z) | ((unsigned)f2bf(b.w) << 16);
        tab[i] = o;
    }
}

// ---------- bf16 gather path: 16 lanes per walk, 16 B/lane ----------
__global__ __launch_bounds__(256) void mp2v_loss_bf16_kernel(
    const uint4* __restrict__ tab,       // bf16 rows, 128 bf16 = 16 uint4 each
    const int* __restrict__ pos_rw,
    const int* __restrict__ neg_rw,
    int n_pos, int n_neg,
    float* __restrict__ acc)
{
    const int tid = threadIdx.x;
    const int sub = tid & 15;                     // lane within 16-lane group
    const int grp = blockIdx.x * (blockDim.x >> 4) + (tid >> 4);
    const int n_grp = gridDim.x * (blockDim.x >> 4);
    const int total = n_pos + n_neg;

    float acc_pos = 0.0f;
    float acc_neg = 0.0f;

    for (int w = grp; w < total; w += n_grp) {
        const bool is_pos = (w < n_pos);
        const int* rw = is_pos ? (pos_rw + (size_t)w * WALK_LEN)
                               : (neg_rw + (size_t)(w - n_pos) * WALK_LEN);
        const int i0 = rw[0];
        const uint4 hsv = tab[(size_t)i0 * 16 + sub];
        // unpack start row fragment once (8 floats), reused for 6 partners
        float hs[8];
        hs[0] = bf_lo(hsv.x); hs[1] = bf_hi(hsv.x);
        hs[2] = bf_lo(hsv.y); hs[3] = bf_hi(hsv.y);
        hs[4] = bf_lo(hsv.z); hs[5] = bf_hi(hsv.z);
        hs[6] = bf_lo(hsv.w); hs[7] = bf_hi(hsv.w);

        // issue all 6 partner loads before any reduction
        uint4 hr[6];
        #pragma unroll
        for (int c = 0; c < 6; ++c) {
            const int ic = rw[c + 1];
            hr[c] = tab[(size_t)ic * 16 + sub];
        }

        #pragma unroll
        for (int c = 0; c < 6; ++c) {
            float p;
            p  = hs[0] * bf_lo(hr[c].x);
            p += hs[1] * bf_hi(hr[c].x);
            p += hs[2] * bf_lo(hr[c].y);
            p += hs[3] * bf_hi(hr[c].y);
            p += hs[4] * bf_lo(hr[c].z);
            p += hs[5] * bf_hi(hr[c].z);
            p += hs[6] * bf_lo(hr[c].w);
            p += hs[7] * bf_hi(hr[c].w);
            // reduce across 16-lane group
            p += __shfl_xor(p, 1);
            p += __shfl_xor(p, 2);
            p += __shfl_xor(p, 4);
            p += __shfl_xor(p, 8);
            const float s = 1.0f / (1.0f + __expf(-p));
            const float term = is_pos ? __logf(s + EPSF)
                                      : __logf(1.0f - s + EPSF);
            if (sub == 0) {
                if (is_pos) acc_pos += term;
                else        acc_neg += term;
            }
        }
    }

    // 64-lane wave reduction (only lanes with sub==0 hold nonzero)
    #pragma unroll
    for (int m = 1; m < 64; m <<= 1) {
        acc_pos += __shfl_xor(acc_pos, m);
        acc_neg += __shfl_xor(acc_neg, m);
    }
    __shared__ float s_pos[4];
    __shared__ float s_neg[4];
    const int wave = tid >> 6;
    if ((tid & 63) == 0) { s_pos[wave] = acc_pos; s_neg[wave] = acc_neg; }
    __syncthreads();
    if (tid == 0) {
        atomicAdd(&acc[0], s_pos[0] + s_pos[1] + s_pos[2] + s_pos[3]);
        atomicAdd(&acc[1], s_neg[0] + s_neg[1] + s_neg[2] + s_neg[3]);
    }
}

// ---------- f32 fallback path (proven R1 kernel) ----------
__global__ __launch_bounds__(256) void mp2v_loss_f32_kernel(
    const float* __restrict__ emb,
    const int* __restrict__ pos_rw,
    const int* __restrict__ neg_rw,
    int n_pos, int n_neg,
    float* __restrict__ acc)
{
    const int tid = threadIdx.x;
    const int sub = tid & 31;
    const int ghw = blockIdx.x * (blockDim.x >> 5) + (tid >> 5);
    const int n_hw = gridDim.x * (blockDim.x >> 5);
    const int total = n_pos + n_neg;
    float acc_pos = 0.0f, acc_neg = 0.0f;

    for (int w = ghw; w < total; w += n_hw) {
        const bool is_pos = (w < n_pos);
        const int* rw = is_pos ? (pos_rw + (size_t)w * WALK_LEN)
                               : (neg_rw + (size_t)(w - n_pos) * WALK_LEN);
        const float4 hsv = ((const float4*)(emb + (size_t)rw[0] * DIM))[sub];
        #pragma unroll
        for (int c = 1; c < WALK_LEN; ++c) {
            const float4 hr = ((const float4*)(emb + (size_t)rw[c] * DIM))[sub];
            float p = hsv.x * hr.x + hsv.y * hr.y + hsv.z * hr.z + hsv.w * hr.w;
            p += __shfl_xor(p, 1);  p += __shfl_xor(p, 2);
            p += __shfl_xor(p, 4);  p += __shfl_xor(p, 8);
            p += __shfl_xor(p, 16);
            const float s = 1.0f / (1.0f + __expf(-p));
            const float term = is_pos ? __logf(s + EPSF) : __logf(1.0f - s + EPSF);
            if (sub == 0) { if (is_pos) acc_pos += term; else acc_neg += term; }
        }
    }
    #pragma unroll
    for (int m = 1; m < 64; m <<= 1) {
        acc_pos += __shfl_xor(acc_pos, m);
        acc_neg += __shfl_xor(acc_neg, m);
    }
    __shared__ float s_pos[4];
    __shared__ float s_neg[4];
    const int wave = tid >> 6;
    if ((tid & 63) == 0) { s_pos[wave] = acc_pos; s_neg[wave] = acc_neg; }
    __syncthreads();
    if (tid == 0) {
        atomicAdd(&acc[0], s_pos[0] + s_pos[1] + s_pos[2] + s_pos[3]);
        atomicAdd(&acc[1], s_neg[0] + s_neg[1] + s_neg[2] + s_neg[3]);
    }
}

__global__ void mp2v_finalize_kernel(const float* __restrict__ acc,
                                     float* __restrict__ out,
                                     float inv_pos, float inv_neg)
{
    out[0] = -(acc[0] * inv_pos) - (acc[1] * inv_neg);
}

extern "C" void kernel_launch(void* const* d_in, const int* in_sizes, int n_in,
                              void* d_out, int out_size, void* d_ws, size_t ws_size,
                              hipStream_t stream) {
    const float* emb    = (const float*)d_in[0];
    const int*   pos_rw = (const int*)d_in[1];
    const int*   neg_rw = (const int*)d_in[2];
    const int n_pos = in_sizes[1] / WALK_LEN;   // 81920
    const int n_neg = in_sizes[2] / WALK_LEN;   // 409600

    float* acc = (float*)d_ws;
    hipMemsetAsync(acc, 0, 2 * sizeof(float), stream);

    const size_t need = (size_t)TAB_OFF + (size_t)N_ELEM * 2;
    if (ws_size >= need) {
        uint4* tab = (uint4*)((char*)d_ws + TAB_OFF);
        mp2v_convert_kernel<<<4096, 256, 0, stream>>>(emb, tab, N_ELEM / 8);
        mp2v_loss_bf16_kernel<<<3840, 256, 0, stream>>>(tab, pos_rw, neg_rw,
                                                        n_pos, n_neg, acc);
    } else {
        mp2v_loss_f32_kernel<<<2560, 256, 0, stream>>>(emb, pos_rw, neg_rw,
                                                       n_pos, n_neg, acc);
    }

    const float inv_pos = 1.0f / (float)(n_pos * (WALK_LEN - 1));
    const float inv_neg = 1.0f / (float)(n_neg * (WALK_LEN - 1));
    mp2v_finalize_kernel<<<1, 1, 0, stream>>>(acc, (float*)d_out,
                                              inv_pos, inv_neg);
}

// Round 4
// 510.985 us; speedup vs baseline: 1.2313x; 1.0121x over previous
//
#include <hip/hip_runtime.h>

#define WALK_LEN 7
#define DIM 128
#define EPSF 1e-15f
#define N_ELEM 64000128      // 500001 * 128
#define TAB_OFF 256          // fp16 table offset within d_ws (bytes)

typedef __fp16 half2_t __attribute__((ext_vector_type(2)));

__device__ __forceinline__ half2_t u2h2(unsigned u) {
    return __builtin_bit_cast(half2_t, u);
}
__device__ __forceinline__ unsigned h22u(half2_t h) {
    return __builtin_bit_cast(unsigned, h);
}

__device__ __forceinline__ float dot8(uint4 a, uint4 b, float c) {
#if __has_builtin(__builtin_amdgcn_fdot2)
    c = __builtin_amdgcn_fdot2(u2h2(a.x), u2h2(b.x), c, false);
    c = __builtin_amdgcn_fdot2(u2h2(a.y), u2h2(b.y), c, false);
    c = __builtin_amdgcn_fdot2(u2h2(a.z), u2h2(b.z), c, false);
    c = __builtin_amdgcn_fdot2(u2h2(a.w), u2h2(b.w), c, false);
#else
    half2_t ax = u2h2(a.x), bx = u2h2(b.x);
    half2_t ay = u2h2(a.y), by = u2h2(b.y);
    half2_t az = u2h2(a.z), bz = u2h2(b.z);
    half2_t aw = u2h2(a.w), bw = u2h2(b.w);
    c += (float)ax[0]*(float)bx[0] + (float)ax[1]*(float)bx[1];
    c += (float)ay[0]*(float)by[0] + (float)ay[1]*(float)by[1];
    c += (float)az[0]*(float)bz[0] + (float)az[1]*(float)bz[1];
    c += (float)aw[0]*(float)bw[0] + (float)aw[1]*(float)bw[1];
#endif
    return c;
}

// Streaming convert f32 -> fp16 via v_cvt_pkrtz: 2x float4 in, uint4 (8 halves) out.
__global__ __launch_bounds__(256) void mp2v_convert_kernel(
    const float4* __restrict__ emb4, uint4* __restrict__ tab, int n8)
{
    int i = blockIdx.x * blockDim.x + threadIdx.x;
    const int stride = gridDim.x * blockDim.x;
    for (; i < n8; i += stride) {
        const float4 a = emb4[2 * i];
        const float4 b = emb4[2 * i + 1];
        uint4 o;
        o.x = h22u(__builtin_amdgcn_cvt_pkrtz(a.x, a.y));
        o.y = h22u(__builtin_amdgcn_cvt_pkrtz(a.z, a.w));
        o.z = h22u(__builtin_amdgcn_cvt_pkrtz(b.x, b.y));
        o.w = h22u(__builtin_amdgcn_cvt_pkrtz(b.z, b.w));
        tab[i] = o;
    }
}

// 16 lanes per walk; each lane loads uint4 = 8 fp16 of the 128-elem row.
__global__ __launch_bounds__(256) void mp2v_loss_f16_kernel(
    const uint4* __restrict__ tab,
    const int* __restrict__ pos_rw,
    const int* __restrict__ neg_rw,
    int n_pos, int n_neg,
    float* __restrict__ acc)
{
    const int tid = threadIdx.x;
    const int sub = tid & 15;
    const int grp = blockIdx.x * (blockDim.x >> 4) + (tid >> 4);
    const int n_grp = gridDim.x * (blockDim.x >> 4);
    const int total = n_pos + n_neg;

    float acc_pos = 0.0f;
    float acc_neg = 0.0f;

    for (int w = grp; w < total; w += n_grp) {
        const bool is_pos = (w < n_pos);
        const int* rw = is_pos ? (pos_rw + (size_t)w * WALK_LEN)
                               : (neg_rw + (size_t)(w - n_pos) * WALK_LEN);
        const uint4 hs = tab[(size_t)rw[0] * 16 + sub];

        uint4 hr[6];
        #pragma unroll
        for (int c = 0; c < 6; ++c)
            hr[c] = tab[(size_t)rw[c + 1] * 16 + sub];

        float p[6];
        #pragma unroll
        for (int c = 0; c < 6; ++c) {
            float d = dot8(hs, hr[c], 0.0f);
            // reduce across the 16-lane group; all lanes end with the full dot
            d += __shfl_xor(d, 1);
            d += __shfl_xor(d, 2);
            d += __shfl_xor(d, 4);
            d += __shfl_xor(d, 8);
            p[c] = d;
        }

        // lane sub (<6) transforms dot #sub: 1 exp + 1 log per walk instead of 6
        float myp = p[0];
        myp = (sub == 1) ? p[1] : myp;
        myp = (sub == 2) ? p[2] : myp;
        myp = (sub == 3) ? p[3] : myp;
        myp = (sub == 4) ? p[4] : myp;
        myp = (sub == 5) ? p[5] : myp;
        const float s = 1.0f / (1.0f + __expf(-myp));
        const float term = is_pos ? __logf(s + EPSF) : __logf(1.0f - s + EPSF);
        if (sub < 6) {
            if (is_pos) acc_pos += term;
            else        acc_neg += term;
        }
    }

    // 64-lane wave reduction
    #pragma unroll
    for (int m = 1; m < 64; m <<= 1) {
        acc_pos += __shfl_xor(acc_pos, m);
        acc_neg += __shfl_xor(acc_neg, m);
    }
    __shared__ float s_pos[4];
    __shared__ float s_neg[4];
    const int wave = tid >> 6;
    if ((tid & 63) == 0) { s_pos[wave] = acc_pos; s_neg[wave] = acc_neg; }
    __syncthreads();
    if (tid == 0) {
        atomicAdd(&acc[0], s_pos[0] + s_pos[1] + s_pos[2] + s_pos[3]);
        atomicAdd(&acc[1], s_neg[0] + s_neg[1] + s_neg[2] + s_neg[3]);
    }
}

// f32 fallback (ws too small) — proven R1 kernel
__global__ __launch_bounds__(256) void mp2v_loss_f32_kernel(
    const float* __restrict__ emb,
    const int* __restrict__ pos_rw,
    const int* __restrict__ neg_rw,
    int n_pos, int n_neg,
    float* __restrict__ acc)
{
    const int tid = threadIdx.x;
    const int sub = tid & 31;
    const int ghw = blockIdx.x * (blockDim.x >> 5) + (tid >> 5);
    const int n_hw = gridDim.x * (blockDim.x >> 5);
    const int total = n_pos + n_neg;
    float acc_pos = 0.0f, acc_neg = 0.0f;

    for (int w = ghw; w < total; w += n_hw) {
        const bool is_pos = (w < n_pos);
        const int* rw = is_pos ? (pos_rw + (size_t)w * WALK_LEN)
                               : (neg_rw + (size_t)(w - n_pos) * WALK_LEN);
        const float4 hsv = ((const float4*)(emb + (size_t)rw[0] * DIM))[sub];
        #pragma unroll
        for (int c = 1; c < WALK_LEN; ++c) {
            const float4 hr = ((const float4*)(emb + (size_t)rw[c] * DIM))[sub];
            float p = hsv.x * hr.x + hsv.y * hr.y + hsv.z * hr.z + hsv.w * hr.w;
            p += __shfl_xor(p, 1);  p += __shfl_xor(p, 2);
            p += __shfl_xor(p, 4);  p += __shfl_xor(p, 8);
            p += __shfl_xor(p, 16);
            const float s = 1.0f / (1.0f + __expf(-p));
            const float term = is_pos ? __logf(s + EPSF) : __logf(1.0f - s + EPSF);
            if (sub == 0) { if (is_pos) acc_pos += term; else acc_neg += term; }
        }
    }
    #pragma unroll
    for (int m = 1; m < 64; m <<= 1) {
        acc_pos += __shfl_xor(acc_pos, m);
        acc_neg += __shfl_xor(acc_neg, m);
    }
    __shared__ float s_pos[4];
    __shared__ float s_neg[4];
    const int wave = tid >> 6;
    if ((tid & 63) == 0) { s_pos[wave] = acc_pos; s_neg[wave] = acc_neg; }
    __syncthreads();
    if (tid == 0) {
        atomicAdd(&acc[0], s_pos[0] + s_pos[1] + s_pos[2] + s_pos[3]);
        atomicAdd(&acc[1], s_neg[0] + s_neg[1] + s_neg[2] + s_neg[3]);
    }
}

__global__ void mp2v_finalize_kernel(const float* __restrict__ acc,
                                     float* __restrict__ out,
                                     float inv_pos, float inv_neg)
{
    out[0] = -(acc[0] * inv_pos) - (acc[1] * inv_neg);
}

extern "C" void kernel_launch(void* const* d_in, const int* in_sizes, int n_in,
                              void* d_out, int out_size, void* d_ws, size_t ws_size,
                              hipStream_t stream) {
    const float* emb    = (const float*)d_in[0];
    const int*   pos_rw = (const int*)d_in[1];
    const int*   neg_rw = (const int*)d_in[2];
    const int n_pos = in_sizes[1] / WALK_LEN;   // 81920
    const int n_neg = in_sizes[2] / WALK_LEN;   // 409600

    float* acc = (float*)d_ws;
    (void)hipMemsetAsync(acc, 0, 2 * sizeof(float), stream);

    const size_t need = (size_t)TAB_OFF + (size_t)N_ELEM * 2;
    if (ws_size >= need) {
        uint4* tab = (uint4*)((char*)d_ws + TAB_OFF);
        mp2v_convert_kernel<<<8192, 256, 0, stream>>>((const float4*)emb, tab,
                                                      N_ELEM / 8);
        mp2v_loss_f16_kernel<<<3840, 256, 0, stream>>>(tab, pos_rw, neg_rw,
                                                       n_pos, n_neg, acc);
    } else {
        mp2v_loss_f32_kernel<<<2560, 256, 0, stream>>>(emb, pos_rw, neg_rw,
                                                       n_pos, n_neg, acc);
    }

    const float inv_pos = 1.0f / (float)(n_pos * (WALK_LEN - 1));
    const float inv_neg = 1.0f / (float)(n_neg * (WALK_LEN - 1));
    mp2v_finalize_kernel<<<1, 1, 0, stream>>>(acc, (float*)d_out,
                                              inv_pos, inv_neg);
}